// Round 1
// baseline (129.860 us; speedup 1.0000x reference)
//
#include <hip/hip_runtime.h>

// LogSparse attention: B=4, L=2048, H=8, D=64, fp32.
// Each query i attends only to {i} ∪ {i - 2^k : 2^k <= i}  (<= 12 positions).
// One 64-lane wave per (b,i,h) row; lane == d index.

constexpr int B = 4, L = 2048, H = 8, D = 64;
constexpr int NPOS = 12;  // 1 (self) + 11 power-of-2 offsets (1..1024)

__global__ __launch_bounds__(256) void logsparse_attn_kernel(
    const float* __restrict__ Q, const float* __restrict__ K,
    const float* __restrict__ V, float* __restrict__ O) {
  const int gtid = blockIdx.x * blockDim.x + threadIdx.x;
  const int row  = gtid >> 6;          // (b*L + i)*H + h
  const int lane = threadIdx.x & 63;
  if (row >= B * L * H) return;

  const int h  = row % H;
  const int bi = row / H;              // b*L + i
  const int i  = bi % L;
  const int b  = bi / L;

  const float qd = Q[(size_t)row * D + lane];
  const float scale = 0.125f;          // 1/sqrt(64)

  float sc[NPOS];
  #pragma unroll
  for (int t = 0; t < NPOS; ++t) {
    const int off   = (t == 0) ? 0 : (1 << (t - 1));
    const bool valid = (off <= i);
    const int j     = valid ? (i - off) : i;   // clamp to a safe, cached addr
    const float kd  = K[(((size_t)(b * L + j)) * H + h) * D + lane];
    float prod = qd * kd;
    // 64-lane butterfly sum
    prod += __shfl_xor(prod, 32, 64);
    prod += __shfl_xor(prod, 16, 64);
    prod += __shfl_xor(prod, 8, 64);
    prod += __shfl_xor(prod, 4, 64);
    prod += __shfl_xor(prod, 2, 64);
    prod += __shfl_xor(prod, 1, 64);
    sc[t] = valid ? prod * scale : -INFINITY;
  }

  // softmax over the (<=12) scores; sc[0] (self) is always valid -> finite max
  float m = sc[0];
  #pragma unroll
  for (int t = 1; t < NPOS; ++t) m = fmaxf(m, sc[t]);
  float denom = 0.f;
  #pragma unroll
  for (int t = 0; t < NPOS; ++t) {
    sc[t] = __expf(sc[t] - m);   // exp(-inf - m) == 0 for invalid slots
    denom += sc[t];
  }
  const float inv = 1.0f / denom;

  float acc = 0.f;
  #pragma unroll
  for (int t = 0; t < NPOS; ++t) {
    const int off   = (t == 0) ? 0 : (1 << (t - 1));
    const bool valid = (off <= i);
    const int j     = valid ? (i - off) : i;
    const float vd  = V[(((size_t)(b * L + j)) * H + h) * D + lane];
    acc += sc[t] * vd;           // sc[t]==0 for invalid -> no contribution
  }
  O[(size_t)row * D + lane] = acc * inv;
}

extern "C" void kernel_launch(void* const* d_in, const int* in_sizes, int n_in,
                              void* d_out, int out_size, void* d_ws, size_t ws_size,
                              hipStream_t stream) {
  const float* Q = (const float*)d_in[0];
  const float* K = (const float*)d_in[1];
  const float* V = (const float*)d_in[2];
  float* O = (float*)d_out;

  const int rows = B * L * H;                 // 65536 waves
  const int threads = 256;                    // 4 waves / block
  const int blocks = (rows * 64) / threads;   // 16384 blocks
  logsparse_attn_kernel<<<blocks, threads, 0, stream>>>(Q, K, V, O);
}

// Round 2
// 102.592 us; speedup vs baseline: 1.2658x; 1.2658x over previous
//
#include <hip/hip_runtime.h>

// LogSparse attention: B=4, L=2048, H=8, D=64, fp32.
// Query i attends to {i} ∪ {i - 2^k : 2^k <= i}  (<= 12 positions).
// One wave handles 4 rows: same (b,i), heads hbase..hbase+3.
// lane = g*16 + dsub: g = head sub-index (0..3), dsub = d/4 (0..15).
// Each lane holds a float4 of the 64-wide feature vector.

constexpr int B = 4, L = 2048, H = 8, D = 64;
constexpr int NPOS = 12;  // self + offsets 1,2,4,...,1024

__global__ __launch_bounds__(256) void logsparse_attn_kernel(
    const float* __restrict__ Q, const float* __restrict__ K,
    const float* __restrict__ V, float* __restrict__ O) {
  const int wid  = (blockIdx.x * blockDim.x + threadIdx.x) >> 6;  // wave id
  const int lane = threadIdx.x & 63;
  const int g    = lane >> 4;          // which head within the 4
  const int dsub = lane & 15;          // which float4 of D

  const int bi    = wid >> 1;          // b*L + i
  const int hbase = (wid & 1) * 4;     // H=8 -> two waves per (b,i)
  const int i     = bi & (L - 1);

  // flat element index of this lane's (b,i,h,d0)
  const size_t base = ((size_t)bi * H + (hbase + g)) * D + dsub * 4;

  const float4 q4 = *reinterpret_cast<const float4*>(Q + base);

  float sc[NPOS];
  #pragma unroll
  for (int t = 0; t < NPOS; ++t) {
    const int off    = (t == 0) ? 0 : (1 << (t - 1));
    const bool valid = (off <= i);                       // wave-uniform
    const size_t kb  = valid ? (base - (size_t)off * (H * D)) : base;
    const float4 k4  = *reinterpret_cast<const float4*>(K + kb);
    float p = q4.x * k4.x + q4.y * k4.y + q4.z * k4.z + q4.w * k4.w;
    // reduce across the 16 lanes of this head-group (masks < 16 stay in-group)
    p += __shfl_xor(p, 1, 64);
    p += __shfl_xor(p, 2, 64);
    p += __shfl_xor(p, 4, 64);
    p += __shfl_xor(p, 8, 64);
    sc[t] = valid ? p * 0.125f : -INFINITY;
  }

  // per-group softmax (scores replicated across the 16 lanes of the group)
  float m = sc[0];
  #pragma unroll
  for (int t = 1; t < NPOS; ++t) m = fmaxf(m, sc[t]);
  float denom = 0.f;
  #pragma unroll
  for (int t = 0; t < NPOS; ++t) {
    sc[t] = __expf(sc[t] - m);      // exp(-inf) == 0 for invalid slots
    denom += sc[t];
  }
  const float inv = 1.0f / denom;

  float4 acc = make_float4(0.f, 0.f, 0.f, 0.f);
  #pragma unroll
  for (int t = 0; t < NPOS; ++t) {
    const int off    = (t == 0) ? 0 : (1 << (t - 1));
    const bool valid = (off <= i);
    const size_t vb  = valid ? (base - (size_t)off * (H * D)) : base;
    const float4 v4  = *reinterpret_cast<const float4*>(V + vb);
    acc.x += sc[t] * v4.x;
    acc.y += sc[t] * v4.y;
    acc.z += sc[t] * v4.z;
    acc.w += sc[t] * v4.w;
  }
  acc.x *= inv; acc.y *= inv; acc.z *= inv; acc.w *= inv;
  *reinterpret_cast<float4*>(O + base) = acc;
}

extern "C" void kernel_launch(void* const* d_in, const int* in_sizes, int n_in,
                              void* d_out, int out_size, void* d_ws, size_t ws_size,
                              hipStream_t stream) {
  const float* Q = (const float*)d_in[0];
  const float* K = (const float*)d_in[1];
  const float* V = (const float*)d_in[2];
  float* O = (float*)d_out;

  const int rows    = B * L * H;        // 65536
  const int waves   = rows / 4;         // 16384 (4 rows per wave)
  const int threads = 256;              // 4 waves per block
  const int blocks  = (waves * 64) / threads;  // 4096
  logsparse_attn_kernel<<<blocks, threads, 0, stream>>>(Q, K, V, O);
}